// Round 7
// baseline (3610.971 us; speedup 1.0000x reference)
//
#include <hip/hip_runtime.h>

#define NN 100000
#define NE 3200000
#define DB 256               // dst nodes per bucket
#define NBK 391              // ceil(NN/DB)
#define BCAP 9216            // edge capacity per bucket (mean 8192, +11 sigma)
#define EPB 4096             // edges per partition block
#define NPB 782              // ceil(NE/EPB)

typedef _Float16 half8 __attribute__((ext_vector_type(8)));
typedef float    f32x4 __attribute__((ext_vector_type(4)));

// ---------------- h0 = concat(node_type, LN(onehot@We+be), other), fp16 padded to 32 ----------------
__global__ __launch_bounds__(256) void k_h0(const float* __restrict__ x,
    const float* __restrict__ We, const float* __restrict__ be,
    const float* __restrict__ lg, const float* __restrict__ lb,
    _Float16* __restrict__ h0p)
{
  __shared__ float xs[256 * 35];
  int tid = threadIdx.x;
  int base_node = blockIdx.x * 256;
  int nvalid = NN - base_node; if (nvalid > 256) nvalid = 256;
  int total = nvalid * 35;
  const float* srcp = x + (size_t)base_node * 35;
  for (int j = tid; j < total; j += 256) xs[j] = srcp[j];
  __syncthreads();
  int i = base_node + tid;
  if (i >= NN) return;
  const float* xr = xs + tid * 35;
  float e[8];
  #pragma unroll
  for (int j = 0; j < 8; ++j) e[j] = be[j];
  #pragma unroll
  for (int k = 0; k < 26; ++k) {
    float o = xr[6 + k];
    #pragma unroll
    for (int j = 0; j < 8; ++j) e[j] = fmaf(o, We[k * 8 + j], e[j]);
  }
  float mu = 0.f;
  #pragma unroll
  for (int j = 0; j < 8; ++j) mu += e[j];
  mu *= 0.125f;
  float var = 0.f;
  #pragma unroll
  for (int j = 0; j < 8; ++j) { float d = e[j] - mu; var = fmaf(d, d, var); }
  var *= 0.125f;
  float rs = rsqrtf(var + 1e-5f);

  _Float16 row[32];
  #pragma unroll
  for (int j = 0; j < 6; ++j) row[j] = (_Float16)xr[j];
  #pragma unroll
  for (int j = 0; j < 8; ++j) row[6 + j] = (_Float16)((e[j] - mu) * rs * lg[j] + lb[j]);
  #pragma unroll
  for (int j = 0; j < 3; ++j) row[14 + j] = (_Float16)xr[32 + j];
  #pragma unroll
  for (int j = 17; j < 32; ++j) row[j] = (_Float16)0.f;
  half8* dst = (half8*)(h0p + (size_t)i * 32);
  #pragma unroll
  for (int q = 0; q < 4; ++q) dst[q] = *(half8*)(row + q * 8);
}

// ---------------- partition pass A: bin edges into 256-node dst buckets (padded regions) ----------------
__global__ __launch_bounds__(256) void k_partA(const int* __restrict__ ei,
    int* __restrict__ gcur, int* __restrict__ ebuf)
{
  __shared__ int hist[NBK], lofs[NBK], gb[NBK], cur[NBK];
  __shared__ int sd[256];
  __shared__ int stage[EPB];
  __shared__ unsigned short sbkt[EPB];
  int tid = threadIdx.x;
  int base = blockIdx.x * EPB;
  int n = NE - base; if (n > EPB) n = EPB;
  for (int b = tid; b < NBK; b += 256) hist[b] = 0;
  __syncthreads();
  int s[16], d[16];
  #pragma unroll
  for (int k = 0; k < 16; ++k) {
    int idx = tid + k * 256;
    if (idx < n) {
      s[k] = ei[base + idx];
      d[k] = ei[NE + base + idx];
      atomicAdd(&hist[d[k] >> 8], 1);
    } else { s[k] = -1; d[k] = 0; }
  }
  __syncthreads();
  int b0 = 2 * tid, b1 = 2 * tid + 1;
  int c0 = (b0 < NBK) ? hist[b0] : 0;
  int c1 = (b1 < NBK) ? hist[b1] : 0;
  int ls = c0 + c1;
  sd[tid] = ls; __syncthreads();
  for (int off = 1; off < 256; off <<= 1) {
    int t = (tid >= off) ? sd[tid - off] : 0;
    __syncthreads(); sd[tid] += t; __syncthreads();
  }
  int excl = sd[tid] - ls;
  if (b0 < NBK) { lofs[b0] = excl;      cur[b0] = excl;      if (c0) gb[b0] = b0 * BCAP + atomicAdd(&gcur[b0], c0); }
  if (b1 < NBK) { lofs[b1] = excl + c0; cur[b1] = excl + c0; if (c1) gb[b1] = b1 * BCAP + atomicAdd(&gcur[b1], c1); }
  __syncthreads();
  #pragma unroll
  for (int k = 0; k < 16; ++k) {
    if (s[k] >= 0) {
      int b = d[k] >> 8;
      int p = atomicAdd(&cur[b], 1);
      stage[p] = (s[k] << 8) | (d[k] & 255);
      sbkt[p] = (unsigned short)b;
    }
  }
  __syncthreads();
  for (int p = tid; p < n; p += 256) {
    int b = sbkt[p];
    int pos = gb[b] + (p - lofs[b]);
    if (pos < (b + 1) * BCAP) ebuf[pos] = stage[p];
  }
}

// ---------------- partition pass B: per-bucket sort by src-chunk + degree histogram ----------------
__global__ __launch_bounds__(256) void k_partB(const int* __restrict__ gcur,
    const int* __restrict__ ebuf, int* __restrict__ sebuf, int* __restrict__ degs)
{
  __shared__ int chist[32], ccur[32];
  __shared__ int ddeg[DB];
  __shared__ int lst[BCAP];
  int b = blockIdx.x, tid = threadIdx.x;
  int n = gcur[b]; if (n > BCAP) n = BCAP;
  if (tid < 32) chist[tid] = 0;
  if (tid < DB) ddeg[tid] = 0;
  __syncthreads();
  const int* eb = ebuf + (size_t)b * BCAP;
  for (int e = tid; e < n; e += 256) {
    int w = eb[e];
    atomicAdd(&chist[w >> 20], 1);   // src chunk = src>>12 = w>>20 (25 used)
    atomicAdd(&ddeg[w & 255], 1);
  }
  __syncthreads();
  if (tid == 0) {
    int run = 0;
    for (int c = 0; c < 32; ++c) { int v = chist[c]; ccur[c] = run; run += v; }
  }
  __syncthreads();
  for (int e = tid; e < n; e += 256) {
    int w = eb[e];
    int p = atomicAdd(&ccur[w >> 20], 1);
    lst[p] = w;
  }
  __syncthreads();
  int* sb = sebuf + (size_t)b * BCAP;
  for (int p = tid; p < n; p += 256) sb[p] = lst[p];
  int node = b * DB + tid;
  if (tid < DB && node < NN) degs[node] = ddeg[tid];
}

// ---------------- tiled aggregate: LDS accumulators, src-chunk-ordered sweep ----------------
template <int W>
__global__ __launch_bounds__(256) void k_agg(const _Float16* __restrict__ hin,
    const int* __restrict__ gcur, const int* __restrict__ sebuf,
    const int* __restrict__ degs, _Float16* __restrict__ meanout)
{
  extern __shared__ float sacc[];       // DB * W floats
  int b = blockIdx.x, tid = threadIdx.x;
  int w = tid >> 6, lane = tid & 63;
  for (int k = tid; k < DB * W; k += 256) sacc[k] = 0.f;
  __syncthreads();
  int n = gcur[b]; if (n > BCAP) n = BCAP;
  const int* sb = sebuf + (size_t)b * BCAP;
  int ng = n >> 6;
  for (int g = w; g < ng; g += 4) {
    int wv = sb[g * 64 + lane];
    if (W == 64) {
      #pragma unroll
      for (int j = 0; j < 64; ++j) {
        int we = __builtin_amdgcn_readlane(wv, j);   // uniform
        int src = we >> 8, dl = we & 255;
        float v = (float)hin[(size_t)src * 64 + lane];
        atomicAdd(&sacc[dl * 64 + lane], v);
      }
    } else {
      #pragma unroll
      for (int j = 0; j < 64; j += 2) {
        int we0 = __builtin_amdgcn_readlane(wv, j);
        int we1 = __builtin_amdgcn_readlane(wv, j + 1);
        int we = (lane < 32) ? we0 : we1;
        float v = (float)hin[(size_t)(we >> 8) * 32 + (lane & 31)];
        atomicAdd(&sacc[(we & 255) * 32 + (lane & 31)], v);
      }
    }
  }
  if (w == 0) {                          // tail (< 64 edges)
    for (int e = ng * 64; e < n; ++e) {
      int we = sb[e];
      int src = we >> 8, dl = we & 255;
      if (W == 64) {
        float v = (float)hin[(size_t)src * 64 + lane];
        atomicAdd(&sacc[dl * 64 + lane], v);
      } else if (lane < 32) {
        float v = (float)hin[(size_t)src * 32 + lane];
        atomicAdd(&sacc[dl * 32 + lane], v);
      }
    }
  }
  __syncthreads();
  int base = b * DB;
  if (W == 64) {
    for (int i = w * 64; i < w * 64 + 64; ++i) {
      int node = base + i;
      if (node >= NN) break;
      float dg = fmaxf((float)degs[node], 1.f);
      meanout[(size_t)node * 64 + lane] = (_Float16)(sacc[i * 64 + lane] / dg);
    }
  } else {
    for (int i = w * 64; i < w * 64 + 64; i += 2) {
      if (base + i >= NN) break;
      int node = base + i + (lane >> 5);
      if (node < NN) {
        float dg = fmaxf((float)degs[node], 1.f);
        meanout[(size_t)node * 32 + (lane & 31)] =
            (_Float16)(sacc[(i + (lane >> 5)) * 32 + (lane & 31)] / dg);
      }
    }
  }
}

// ---------------- MFMA MLP with LDS-staged weights: relu(mean@Wl + b + h@Wr [+ h]); FINAL fuses fc ----------------
// mfma_f32_16x16x32_f16: A row=lane&15, k=(lane>>4)*8+j ; D col=lane&15, row=(lane>>4)*4+reg (HW-validated in R6)
template <int W, int KW, bool RES, bool FINAL>
__global__ __launch_bounds__(256) void k_mlp(const _Float16* __restrict__ mean,
    const _Float16* __restrict__ h,
    const float* __restrict__ Wl, const float* __restrict__ bl,
    const float* __restrict__ Wr,
    const float* __restrict__ Wfc, const float* __restrict__ bfc,
    void* __restrict__ outp)
{
  __shared__ _Float16 lwl[64 * W];   // transposed [n][k]
  __shared__ _Float16 lwr[64 * W];
  int tid = threadIdx.x;
  for (int idx = tid; idx < 64 * W; idx += 256) {
    int nn = idx / W, kk = idx % W;                 // W is constexpr pow2
    lwl[idx] = (kk < KW) ? (_Float16)Wl[kk * 64 + nn] : (_Float16)0.f;
    lwr[idx] = (kk < KW) ? (_Float16)Wr[kk * 64 + nn] : (_Float16)0.f;
  }
  __syncthreads();
  constexpr int NKB = W / 32;
  int wv = tid >> 6, lane = tid & 63;
  int c = lane & 15, kg = lane >> 4;

  half8 bwl[4][NKB], bwr[4][NKB];
  #pragma unroll
  for (int nt = 0; nt < 4; ++nt)
    #pragma unroll
    for (int kb = 0; kb < NKB; ++kb) {
      bwl[nt][kb] = *(const half8*)&lwl[(nt * 16 + c) * W + kb * 32 + kg * 8];
      bwr[nt][kb] = *(const half8*)&lwr[(nt * 16 + c) * W + kb * 32 + kg * 8];
    }

  int wavebase = blockIdx.x * 256 + wv * 64;
  #pragma unroll
  for (int ti = 0; ti < 4; ++ti) {
    int tbase = wavebase + ti * 16;     // NN % 16 == 0: tiles fully valid or fully out
    if (tbase >= NN) break;
    half8 am[NKB], ah[NKB];
    #pragma unroll
    for (int kb = 0; kb < NKB; ++kb) {
      am[kb] = *(const half8*)(mean + (size_t)(tbase + c) * W + kb * 32 + kg * 8);
      ah[kb] = *(const half8*)(h    + (size_t)(tbase + c) * W + kb * 32 + kg * 8);
    }
    f32x4 acc[4] = {f32x4{0,0,0,0}, f32x4{0,0,0,0}, f32x4{0,0,0,0}, f32x4{0,0,0,0}};
    #pragma unroll
    for (int nt = 0; nt < 4; ++nt)
      #pragma unroll
      for (int kb = 0; kb < NKB; ++kb) {
        acc[nt] = __builtin_amdgcn_mfma_f32_16x16x32_f16(am[kb], bwl[nt][kb], acc[nt], 0, 0, 0);
        acc[nt] = __builtin_amdgcn_mfma_f32_16x16x32_f16(ah[kb], bwr[nt][kb], acc[nt], 0, 0, 0);
      }
    if (!FINAL) {
      _Float16* hout = (_Float16*)outp;
      #pragma unroll
      for (int nt = 0; nt < 4; ++nt) {
        float bia = bl[nt * 16 + c];
        #pragma unroll
        for (int r = 0; r < 4; ++r) {
          int node = tbase + kg * 4 + r;
          float v = acc[nt][r] + bia;
          if (RES) v += (float)h[(size_t)node * 64 + nt * 16 + c];
          hout[(size_t)node * 64 + nt * 16 + c] = (_Float16)fmaxf(v, 0.f);
        }
      }
    } else {
      #pragma unroll
      for (int r = 0; r < 4; ++r) {
        float p = 0.f;
        #pragma unroll
        for (int nt = 0; nt < 4; ++nt) {
          float v = acc[nt][r] + bl[nt * 16 + c];
          if (RES) v += (float)h[(size_t)(tbase + kg * 4 + r) * 64 + nt * 16 + c];
          v = fmaxf(v, 0.f);
          p = fmaf(v, Wfc[nt * 16 + c], p);
        }
        p += __shfl_xor(p, 1); p += __shfl_xor(p, 2);
        p += __shfl_xor(p, 4); p += __shfl_xor(p, 8);
        if (c == 0) ((float*)outp)[tbase + kg * 4 + r] = p + bfc[0];
      }
    }
  }
}

// ---------------- launch ----------------
extern "C" void kernel_launch(void* const* d_in, const int* in_sizes, int n_in,
                              void* d_out, int out_size, void* d_ws, size_t ws_size,
                              hipStream_t stream)
{
  const float* x   = (const float*)d_in[0];
  const int*   ei  = (const int*)d_in[1];
  const float* We  = (const float*)d_in[2];
  const float* be  = (const float*)d_in[3];
  const float* lg  = (const float*)d_in[4];
  const float* lb  = (const float*)d_in[5];
  const float* Wl1 = (const float*)d_in[6];
  const float* bl1 = (const float*)d_in[7];
  const float* Wr1 = (const float*)d_in[8];
  const float* Wl2 = (const float*)d_in[9];
  const float* bl2 = (const float*)d_in[10];
  const float* Wr2 = (const float*)d_in[11];
  const float* Wl3 = (const float*)d_in[12];
  const float* bl3 = (const float*)d_in[13];
  const float* Wr3 = (const float*)d_in[14];
  const float* Wfc = (const float*)d_in[15];
  const float* bfc = (const float*)d_in[16];
  (void)in_sizes; (void)n_in; (void)out_size; (void)ws_size;

  size_t off = 0;
  auto carve = [&](size_t bytes) -> void* {
    void* p = (char*)d_ws + off;
    off += (bytes + 255) & ~(size_t)255;
    return p;
  };
  _Float16* h0p    = (_Float16*)carve((size_t)NN * 32 * 2);      // 6.4 MB
  _Float16* mean1  = (_Float16*)carve((size_t)NN * 32 * 2);      // 6.4 MB
  _Float16* h1     = (_Float16*)carve((size_t)NN * 64 * 2);      // 12.8 MB
  _Float16* mean23 = (_Float16*)carve((size_t)NN * 64 * 2);      // 12.8 MB
  // union: ebuf (14.4 MB, dead after partB) aliases h2 (12.8 MB, first written layer-2 mlp)
  char*     uni    = (char*)carve((size_t)NBK * BCAP * 4);       // 14.4 MB
  int*      ebuf   = (int*)uni;
  _Float16* h2     = (_Float16*)uni;
  int*      sebuf  = (int*)carve((size_t)NBK * BCAP * 4);        // 14.4 MB
  int*      degs   = (int*)carve((size_t)NN * 4);
  int*      gcur   = (int*)carve((size_t)NBK * 4);

  const int nblk_node = (NN + 255) / 256;   // 391

  hipMemsetAsync(gcur, 0, (size_t)NBK * 4, stream);
  k_h0<<<nblk_node, 256, 0, stream>>>(x, We, be, lg, lb, h0p);
  k_partA<<<NPB, 256, 0, stream>>>(ei, gcur, ebuf);
  k_partB<<<NBK, 256, 0, stream>>>(gcur, ebuf, sebuf, degs);

  // layer 1
  k_agg<32><<<NBK, 256, DB * 32 * 4, stream>>>(h0p, gcur, sebuf, degs, mean1);
  k_mlp<32, 17, false, false><<<nblk_node, 256, 0, stream>>>(mean1, h0p, Wl1, bl1, Wr1, nullptr, nullptr, h1);
  // layer 2
  k_agg<64><<<NBK, 256, DB * 64 * 4, stream>>>(h1, gcur, sebuf, degs, mean23);
  k_mlp<64, 64, true, false><<<nblk_node, 256, 0, stream>>>(mean23, h1, Wl2, bl2, Wr2, nullptr, nullptr, h2);
  // layer 3 + fc
  k_agg<64><<<NBK, 256, DB * 64 * 4, stream>>>(h2, gcur, sebuf, degs, mean23);
  k_mlp<64, 64, true, true><<<nblk_node, 256, 0, stream>>>(mean23, h2, Wl3, bl3, Wr3, Wfc, bfc, d_out);
}

// Round 8
// 398.858 us; speedup vs baseline: 9.0533x; 9.0533x over previous
//
#include <hip/hip_runtime.h>

#define NN 100000
#define NE 3200000
#define NB1 196      // ceil(NN/512): coarse buckets of 512 nodes
#define EPB 4096     // edges per partition block
#define NPB 782      // ceil(NE/EPB)

typedef _Float16 half2v __attribute__((ext_vector_type(2)));
typedef _Float16 half4  __attribute__((ext_vector_type(4)));
typedef _Float16 half8  __attribute__((ext_vector_type(8)));
typedef float    f32x4  __attribute__((ext_vector_type(4)));

// ---------------- h0 = concat(node_type, LN(onehot@We+be), other), fp16 padded to 32 ----------------
__global__ __launch_bounds__(256) void k_h0(const float* __restrict__ x,
    const float* __restrict__ We, const float* __restrict__ be,
    const float* __restrict__ lg, const float* __restrict__ lb,
    _Float16* __restrict__ h0p)
{
  __shared__ float xs[256 * 35];
  int tid = threadIdx.x;
  int base_node = blockIdx.x * 256;
  int nvalid = NN - base_node; if (nvalid > 256) nvalid = 256;
  int total = nvalid * 35;
  const float* srcp = x + (size_t)base_node * 35;
  for (int j = tid; j < total; j += 256) xs[j] = srcp[j];
  __syncthreads();
  int i = base_node + tid;
  if (i >= NN) return;
  const float* xr = xs + tid * 35;
  float e[8];
  #pragma unroll
  for (int j = 0; j < 8; ++j) e[j] = be[j];
  #pragma unroll
  for (int k = 0; k < 26; ++k) {
    float o = xr[6 + k];
    #pragma unroll
    for (int j = 0; j < 8; ++j) e[j] = fmaf(o, We[k * 8 + j], e[j]);
  }
  float mu = 0.f;
  #pragma unroll
  for (int j = 0; j < 8; ++j) mu += e[j];
  mu *= 0.125f;
  float var = 0.f;
  #pragma unroll
  for (int j = 0; j < 8; ++j) { float d = e[j] - mu; var = fmaf(d, d, var); }
  var *= 0.125f;
  float rs = rsqrtf(var + 1e-5f);

  _Float16 row[32];
  #pragma unroll
  for (int j = 0; j < 6; ++j) row[j] = (_Float16)xr[j];
  #pragma unroll
  for (int j = 0; j < 8; ++j) row[6 + j] = (_Float16)((e[j] - mu) * rs * lg[j] + lb[j]);
  #pragma unroll
  for (int j = 0; j < 3; ++j) row[14 + j] = (_Float16)xr[32 + j];
  #pragma unroll
  for (int j = 17; j < 32; ++j) row[j] = (_Float16)0.f;
  half8* dst = (half8*)(h0p + (size_t)i * 32);
  #pragma unroll
  for (int q = 0; q < 4; ++q) dst[q] = *(half8*)(row + q * 8);
}

// ---------------- pass 0: exact coarse histogram ----------------
__global__ __launch_bounds__(256) void k_hist(const int* __restrict__ ei, int* __restrict__ gcur)
{
  __shared__ int hist[NB1];
  int tid = threadIdx.x;
  if (tid < NB1) hist[tid] = 0;
  __syncthreads();
  int base = blockIdx.x * EPB;
  int n = NE - base; if (n > EPB) n = EPB;
  const int* dp = ei + NE + base;
  for (int k = tid; k < n; k += 256) atomicAdd(&hist[dp[k] >> 9], 1);
  __syncthreads();
  if (tid < NB1 && hist[tid]) atomicAdd(&gcur[tid], hist[tid]);
}

// ---------------- pass 0b: scan bucket counts -> bases, reset cursors ----------------
__global__ __launch_bounds__(256) void k_bscan(int* __restrict__ gcur,
    int* __restrict__ bbase, int* __restrict__ row_start)
{
  __shared__ int sd[256];
  int tid = threadIdx.x;
  int v = (tid < NB1) ? gcur[tid] : 0;
  sd[tid] = v; __syncthreads();
  for (int off = 1; off < 256; off <<= 1) {
    int t = (tid >= off) ? sd[tid - off] : 0;
    __syncthreads(); sd[tid] += t; __syncthreads();
  }
  int excl = sd[tid] - v;
  if (tid < NB1) { bbase[tid] = excl; gcur[tid] = excl; }
  if (tid == 0) { bbase[NB1] = NE; row_start[NN] = NE; }
}

// ---------------- pass 1: LDS-binned partition into coarse buckets ----------------
__global__ __launch_bounds__(256) void k_partA(const int* __restrict__ ei,
    int* __restrict__ gcur, int* __restrict__ ebuf)
{
  __shared__ int hist[NB1];
  __shared__ int lofs[NB1];
  __shared__ int gb[NB1];
  __shared__ int cur[NB1];
  __shared__ int sd[256];
  __shared__ int stage[EPB];
  __shared__ unsigned char sbkt[EPB];
  int tid = threadIdx.x;
  int base = blockIdx.x * EPB;
  int n = NE - base; if (n > EPB) n = EPB;
  if (tid < NB1) hist[tid] = 0;
  __syncthreads();
  int s[16], d[16];
  #pragma unroll
  for (int k = 0; k < 16; ++k) {
    int idx = tid + k * 256;
    if (idx < n) {
      s[k] = ei[base + idx];
      d[k] = ei[NE + base + idx];
      atomicAdd(&hist[d[k] >> 9], 1);
    } else { s[k] = -1; d[k] = 0; }
  }
  __syncthreads();
  int v = (tid < NB1) ? hist[tid] : 0;
  sd[tid] = v; __syncthreads();
  for (int off = 1; off < 256; off <<= 1) {
    int t = (tid >= off) ? sd[tid - off] : 0;
    __syncthreads(); sd[tid] += t; __syncthreads();
  }
  int excl = sd[tid] - v;
  if (tid < NB1) {
    lofs[tid] = excl; cur[tid] = excl;
    if (v) gb[tid] = atomicAdd(&gcur[tid], v);
  }
  __syncthreads();
  #pragma unroll
  for (int k = 0; k < 16; ++k) {
    if (s[k] >= 0) {
      int b = d[k] >> 9;
      int p = atomicAdd(&cur[b], 1);
      stage[p] = (s[k] << 9) | (d[k] & 511);
      sbkt[p] = (unsigned char)b;
    }
  }
  __syncthreads();
  for (int p = tid; p < n; p += 256) {
    int b = sbkt[p];
    ebuf[gb[b] + (p - lofs[b])] = stage[p];
  }
}

// ---------------- pass 2: per-bucket CSR build ----------------
__global__ __launch_bounds__(512) void k_partB(const int* __restrict__ bbase,
    const int* __restrict__ ebuf, int* __restrict__ row_start, int* __restrict__ srcs)
{
  __shared__ int lcnt[512];
  __shared__ int sd[512];
  int b = blockIdx.x, tid = threadIdx.x;
  int start = bbase[b], end = bbase[b + 1];
  int n = end - start;
  lcnt[tid] = 0;
  __syncthreads();
  for (int e = tid; e < n; e += 512) atomicAdd(&lcnt[ebuf[start + e] & 511], 1);
  __syncthreads();
  int v = lcnt[tid];
  sd[tid] = v; __syncthreads();
  for (int off = 1; off < 512; off <<= 1) {
    int t = (tid >= off) ? sd[tid - off] : 0;
    __syncthreads(); sd[tid] += t; __syncthreads();
  }
  int excl = sd[tid] - v;
  int node = b * 512 + tid;
  if (node < NN) row_start[node] = start + excl;
  __syncthreads();
  lcnt[tid] = excl;
  __syncthreads();
  for (int e = tid; e < n; e += 512) {
    int w = ebuf[start + e];
    int p = atomicAdd(&lcnt[w & 511], 1);
    srcs[start + p] = w >> 9;
  }
}

// ---------------- aggregate: mean of neighbor rows; 4 edge-groups of 16 lanes ----------------
template <int W>   // W = 32 (4B/lane) or 64 (8B/lane); row = 16 lanes
__global__ __launch_bounds__(256) void k_agg(const _Float16* __restrict__ hin,
    const int* __restrict__ row_start, const int* __restrict__ srcs,
    _Float16* __restrict__ meanout)
{
  constexpr int FP = W / 16;               // floats per lane (2 or 4)
  int wid = (blockIdx.x * 256 + threadIdx.x) >> 6;
  int lane = threadIdx.x & 63;
  if (wid >= NN) return;
  int i = __builtin_amdgcn_readfirstlane(wid);
  int rs = row_start[i], re = row_start[i + 1];
  int m = re - rs;
  int g = lane >> 4;                       // edge subgroup 0..3
  int f = lane & 15;                       // feature-chunk index
  const int* __restrict__ sp = srcs + rs;

  float acc[FP];
  #pragma unroll
  for (int q = 0; q < FP; ++q) acc[q] = 0.f;

  #pragma unroll 4
  for (int e = g; e < m; e += 4) {
    int src = sp[e];
    if (W == 64) {
      half4 v = *(const half4*)(hin + (size_t)src * 64 + f * 4);
      #pragma unroll
      for (int q = 0; q < 4; ++q) acc[q] += (float)v[q];
    } else {
      half2v v = *(const half2v*)(hin + (size_t)src * 32 + f * 2);
      acc[0] += (float)v[0];
      acc[1] += (float)v[1];
    }
  }
  #pragma unroll
  for (int q = 0; q < FP; ++q) {
    acc[q] += __shfl_xor(acc[q], 16);
    acc[q] += __shfl_xor(acc[q], 32);
  }
  float cm = fmaxf((float)m, 1.f);
  if (lane < 16) {
    _Float16 o[FP];
    #pragma unroll
    for (int q = 0; q < FP; ++q) o[q] = (_Float16)(acc[q] / cm);
    if (W == 64) *(half4*)(meanout + (size_t)i * 64 + f * 4) = *(half4*)o;
    else         *(half2v*)(meanout + (size_t)i * 32 + f * 2) = *(half2v*)o;
  }
}

// ---------------- MFMA MLP with LDS-staged weights: relu(mean@Wl + b + h@Wr [+ h]); FINAL fuses fc ----------------
// mfma_f32_16x16x32_f16: A row=lane&15, k=(lane>>4)*8+j ; D col=lane&15, row=(lane>>4)*4+reg (HW-validated R6/R7)
template <int W, int KW, bool RES, bool FINAL>
__global__ __launch_bounds__(256) void k_mlp(const _Float16* __restrict__ mean,
    const _Float16* __restrict__ h,
    const float* __restrict__ Wl, const float* __restrict__ bl,
    const float* __restrict__ Wr,
    const float* __restrict__ Wfc, const float* __restrict__ bfc,
    void* __restrict__ outp)
{
  __shared__ _Float16 lwl[64 * W];   // transposed [n][k]
  __shared__ _Float16 lwr[64 * W];
  int tid = threadIdx.x;
  for (int idx = tid; idx < 64 * W; idx += 256) {
    int nn = idx / W, kk = idx % W;
    lwl[idx] = (kk < KW) ? (_Float16)Wl[kk * 64 + nn] : (_Float16)0.f;
    lwr[idx] = (kk < KW) ? (_Float16)Wr[kk * 64 + nn] : (_Float16)0.f;
  }
  __syncthreads();
  constexpr int NKB = W / 32;
  int wv = tid >> 6, lane = tid & 63;
  int c = lane & 15, kg = lane >> 4;

  half8 bwl[4][NKB], bwr[4][NKB];
  #pragma unroll
  for (int nt = 0; nt < 4; ++nt)
    #pragma unroll
    for (int kb = 0; kb < NKB; ++kb) {
      bwl[nt][kb] = *(const half8*)&lwl[(nt * 16 + c) * W + kb * 32 + kg * 8];
      bwr[nt][kb] = *(const half8*)&lwr[(nt * 16 + c) * W + kb * 32 + kg * 8];
    }

  int wavebase = blockIdx.x * 256 + wv * 64;
  #pragma unroll
  for (int ti = 0; ti < 4; ++ti) {
    int tbase = wavebase + ti * 16;     // NN % 16 == 0: tiles fully valid or fully out
    if (tbase >= NN) break;
    half8 am[NKB], ah[NKB];
    #pragma unroll
    for (int kb = 0; kb < NKB; ++kb) {
      am[kb] = *(const half8*)(mean + (size_t)(tbase + c) * W + kb * 32 + kg * 8);
      ah[kb] = *(const half8*)(h    + (size_t)(tbase + c) * W + kb * 32 + kg * 8);
    }
    f32x4 acc[4] = {f32x4{0,0,0,0}, f32x4{0,0,0,0}, f32x4{0,0,0,0}, f32x4{0,0,0,0}};
    #pragma unroll
    for (int nt = 0; nt < 4; ++nt)
      #pragma unroll
      for (int kb = 0; kb < NKB; ++kb) {
        acc[nt] = __builtin_amdgcn_mfma_f32_16x16x32_f16(am[kb], bwl[nt][kb], acc[nt], 0, 0, 0);
        acc[nt] = __builtin_amdgcn_mfma_f32_16x16x32_f16(ah[kb], bwr[nt][kb], acc[nt], 0, 0, 0);
      }
    if (!FINAL) {
      _Float16* hout = (_Float16*)outp;
      #pragma unroll
      for (int nt = 0; nt < 4; ++nt) {
        float bia = bl[nt * 16 + c];
        #pragma unroll
        for (int r = 0; r < 4; ++r) {
          int node = tbase + kg * 4 + r;
          float v = acc[nt][r] + bia;
          if (RES) v += (float)h[(size_t)node * 64 + nt * 16 + c];
          hout[(size_t)node * 64 + nt * 16 + c] = (_Float16)fmaxf(v, 0.f);
        }
      }
    } else {
      #pragma unroll
      for (int r = 0; r < 4; ++r) {
        float p = 0.f;
        #pragma unroll
        for (int nt = 0; nt < 4; ++nt) {
          float v = acc[nt][r] + bl[nt * 16 + c];
          if (RES) v += (float)h[(size_t)(tbase + kg * 4 + r) * 64 + nt * 16 + c];
          v = fmaxf(v, 0.f);
          p = fmaf(v, Wfc[nt * 16 + c], p);
        }
        p += __shfl_xor(p, 1); p += __shfl_xor(p, 2);
        p += __shfl_xor(p, 4); p += __shfl_xor(p, 8);
        if (c == 0) ((float*)outp)[tbase + kg * 4 + r] = p + bfc[0];
      }
    }
  }
}

// ---------------- launch ----------------
extern "C" void kernel_launch(void* const* d_in, const int* in_sizes, int n_in,
                              void* d_out, int out_size, void* d_ws, size_t ws_size,
                              hipStream_t stream)
{
  const float* x   = (const float*)d_in[0];
  const int*   ei  = (const int*)d_in[1];
  const float* We  = (const float*)d_in[2];
  const float* be  = (const float*)d_in[3];
  const float* lg  = (const float*)d_in[4];
  const float* lb  = (const float*)d_in[5];
  const float* Wl1 = (const float*)d_in[6];
  const float* bl1 = (const float*)d_in[7];
  const float* Wr1 = (const float*)d_in[8];
  const float* Wl2 = (const float*)d_in[9];
  const float* bl2 = (const float*)d_in[10];
  const float* Wr2 = (const float*)d_in[11];
  const float* Wl3 = (const float*)d_in[12];
  const float* bl3 = (const float*)d_in[13];
  const float* Wr3 = (const float*)d_in[14];
  const float* Wfc = (const float*)d_in[15];
  const float* bfc = (const float*)d_in[16];
  (void)in_sizes; (void)n_in; (void)out_size; (void)ws_size;

  size_t off = 0;
  auto carve = [&](size_t bytes) -> void* {
    void* p = (char*)d_ws + off;
    off += (bytes + 255) & ~(size_t)255;
    return p;
  };
  _Float16* h0p    = (_Float16*)carve((size_t)NN * 32 * 2);   // 6.4 MB
  _Float16* mean1  = (_Float16*)carve((size_t)NN * 32 * 2);   // 6.4 MB
  // union: ebuf (12.8 MB, dead after k_partB) aliases h1 (first written by k_mlp layer-1, after partB)
  char*     uni    = (char*)carve((size_t)NE * 4);
  int*      ebuf   = (int*)uni;
  _Float16* h1     = (_Float16*)uni;
  _Float16* mean23 = (_Float16*)carve((size_t)NN * 64 * 2);   // 12.8 MB
  _Float16* h2     = (_Float16*)carve((size_t)NN * 64 * 2);   // 12.8 MB
  int*      row_start = (int*)carve((size_t)(NN + 1) * 4);
  int*      srcs   = (int*)carve((size_t)NE * 4);
  int*      gcur   = (int*)carve((size_t)NB1 * 4);
  int*      bbase  = (int*)carve((size_t)(NB1 + 1) * 4);

  const int nblk_node = (NN + 255) / 256;          // 391
  const int nblk_wave = (NN + 3) / 4;              // 25000 (4 waves/block, 1 wave/node)

  hipMemsetAsync(gcur, 0, (size_t)NB1 * 4, stream);
  k_h0<<<nblk_node, 256, 0, stream>>>(x, We, be, lg, lb, h0p);
  k_hist<<<NPB, 256, 0, stream>>>(ei, gcur);
  k_bscan<<<1, 256, 0, stream>>>(gcur, bbase, row_start);
  k_partA<<<NPB, 256, 0, stream>>>(ei, gcur, ebuf);
  k_partB<<<NB1, 512, 0, stream>>>(bbase, ebuf, row_start, srcs);

  // layer 1
  k_agg<32><<<nblk_wave, 256, 0, stream>>>(h0p, row_start, srcs, mean1);
  k_mlp<32, 17, false, false><<<nblk_node, 256, 0, stream>>>(mean1, h0p, Wl1, bl1, Wr1, nullptr, nullptr, h1);
  // layer 2
  k_agg<64><<<nblk_wave, 256, 0, stream>>>(h1, row_start, srcs, mean23);
  k_mlp<64, 64, true, false><<<nblk_node, 256, 0, stream>>>(mean23, h1, Wl2, bl2, Wr2, nullptr, nullptr, h2);
  // layer 3 + fc
  k_agg<64><<<nblk_wave, 256, 0, stream>>>(h2, row_start, srcs, mean23);
  k_mlp<64, 64, true, true><<<nblk_node, 256, 0, stream>>>(mean23, h2, Wl3, bl3, Wr3, Wfc, bfc, d_out);
}

// Round 9
// 369.857 us; speedup vs baseline: 9.7632x; 1.0784x over previous
//
#include <hip/hip_runtime.h>

#define NN 100000
#define NE 3200000
#define NB1 196        // ceil(NN/512): buckets of 512 dst nodes
#define BCAP2 17664    // padded bucket capacity: mean 16384 + ~10 sigma, %64==0
#define EPB 4096       // edges per partition block
#define NPB 782        // ceil(NE/EPB)

typedef _Float16 half8 __attribute__((ext_vector_type(8)));
typedef float    f32x4 __attribute__((ext_vector_type(4)));

// ---------------- h0 = concat(node_type, LN(onehot@We+be), other), fp16 padded to 32 ----------------
__global__ __launch_bounds__(256) void k_h0(const float* __restrict__ x,
    const float* __restrict__ We, const float* __restrict__ be,
    const float* __restrict__ lg, const float* __restrict__ lb,
    _Float16* __restrict__ h0p)
{
  __shared__ float xs[256 * 35];
  int tid = threadIdx.x;
  int base_node = blockIdx.x * 256;
  int nvalid = NN - base_node; if (nvalid > 256) nvalid = 256;
  int total = nvalid * 35;
  const float* srcp = x + (size_t)base_node * 35;
  for (int j = tid; j < total; j += 256) xs[j] = srcp[j];
  __syncthreads();
  int i = base_node + tid;
  if (i >= NN) return;
  const float* xr = xs + tid * 35;
  float e[8];
  #pragma unroll
  for (int j = 0; j < 8; ++j) e[j] = be[j];
  #pragma unroll
  for (int k = 0; k < 26; ++k) {
    float o = xr[6 + k];
    #pragma unroll
    for (int j = 0; j < 8; ++j) e[j] = fmaf(o, We[k * 8 + j], e[j]);
  }
  float mu = 0.f;
  #pragma unroll
  for (int j = 0; j < 8; ++j) mu += e[j];
  mu *= 0.125f;
  float var = 0.f;
  #pragma unroll
  for (int j = 0; j < 8; ++j) { float d = e[j] - mu; var = fmaf(d, d, var); }
  var *= 0.125f;
  float rs = rsqrtf(var + 1e-5f);

  _Float16 row[32];
  #pragma unroll
  for (int j = 0; j < 6; ++j) row[j] = (_Float16)xr[j];
  #pragma unroll
  for (int j = 0; j < 8; ++j) row[6 + j] = (_Float16)((e[j] - mu) * rs * lg[j] + lb[j]);
  #pragma unroll
  for (int j = 0; j < 3; ++j) row[14 + j] = (_Float16)xr[32 + j];
  #pragma unroll
  for (int j = 17; j < 32; ++j) row[j] = (_Float16)0.f;
  half8* dst = (half8*)(h0p + (size_t)i * 32);
  #pragma unroll
  for (int q = 0; q < 4; ++q) dst[q] = *(half8*)(row + q * 8);
}

// ---------------- pass 1: LDS-binned partition into PADDED 512-node buckets ----------------
__global__ __launch_bounds__(256) void k_partA(const int* __restrict__ ei,
    int* __restrict__ gcur, int* __restrict__ ebuf)
{
  __shared__ int hist[NB1];
  __shared__ int lofs[NB1];
  __shared__ int gb[NB1];
  __shared__ int cur[NB1];
  __shared__ int sd[256];
  __shared__ int stage[EPB];
  __shared__ unsigned char sbkt[EPB];
  int tid = threadIdx.x;
  int base = blockIdx.x * EPB;
  int n = NE - base; if (n > EPB) n = EPB;
  if (tid < NB1) hist[tid] = 0;
  __syncthreads();
  int s[16], d[16];
  #pragma unroll
  for (int k = 0; k < 16; ++k) {
    int idx = tid + k * 256;
    if (idx < n) {
      s[k] = ei[base + idx];
      d[k] = ei[NE + base + idx];
      atomicAdd(&hist[d[k] >> 9], 1);
    } else { s[k] = -1; d[k] = 0; }
  }
  __syncthreads();
  int v = (tid < NB1) ? hist[tid] : 0;
  sd[tid] = v; __syncthreads();
  for (int off = 1; off < 256; off <<= 1) {
    int t = (tid >= off) ? sd[tid - off] : 0;
    __syncthreads(); sd[tid] += t; __syncthreads();
  }
  int excl = sd[tid] - v;
  if (tid < NB1) {
    lofs[tid] = excl; cur[tid] = excl;
    if (v) gb[tid] = tid * BCAP2 + atomicAdd(&gcur[tid], v);
  }
  __syncthreads();
  #pragma unroll
  for (int k = 0; k < 16; ++k) {
    if (s[k] >= 0) {
      int b = d[k] >> 9;
      int p = atomicAdd(&cur[b], 1);
      stage[p] = (s[k] << 9) | (d[k] & 511);
      sbkt[p] = (unsigned char)b;
    }
  }
  __syncthreads();
  for (int p = tid; p < n; p += 256) {
    int b = sbkt[p];
    int pos = gb[b] + (p - lofs[b]);
    if (pos < (b + 1) * BCAP2) ebuf[pos] = stage[p];   // overflow guard (P ~ 0)
  }
}

// ---------------- pass 2: per-bucket CSR build -> rowinfo{rs,m} + compact srcs ----------------
__global__ __launch_bounds__(512) void k_partB(const int* __restrict__ gcur,
    const int* __restrict__ ebuf, int2* __restrict__ rowinfo, int* __restrict__ srcs)
{
  __shared__ int lcnt[512];
  __shared__ int sd[512];
  int b = blockIdx.x, tid = threadIdx.x;
  int n = gcur[b]; if (n > BCAP2) n = BCAP2;
  const int* eb = ebuf + (size_t)b * BCAP2;
  lcnt[tid] = 0;
  __syncthreads();
  for (int e = tid; e < n; e += 512) atomicAdd(&lcnt[eb[e] & 511], 1);
  __syncthreads();
  int v = lcnt[tid];
  sd[tid] = v; __syncthreads();
  for (int off = 1; off < 512; off <<= 1) {
    int t = (tid >= off) ? sd[tid - off] : 0;
    __syncthreads(); sd[tid] += t; __syncthreads();
  }
  int excl = sd[tid] - v;
  int node = b * 512 + tid;
  if (node < NN) rowinfo[node] = make_int2(b * BCAP2 + excl, v);
  __syncthreads();
  lcnt[tid] = excl;
  __syncthreads();
  for (int e = tid; e < n; e += 512) {
    int w = eb[e];
    int p = atomicAdd(&lcnt[w & 511], 1);
    srcs[(size_t)b * BCAP2 + p] = w >> 9;
  }
}

// ---------------- aggregate: mean of neighbor rows; 16B/lane, NG edges in flight ----------------
template <int W>   // W=64: 8 groups x 8 lanes; W=32: 16 groups x 4 lanes
__global__ __launch_bounds__(256) void k_agg(const _Float16* __restrict__ hin,
    const int2* __restrict__ rowinfo, const int* __restrict__ srcs,
    _Float16* __restrict__ meanout)
{
  constexpr int GL = W / 8;      // lanes per row (16B each)
  constexpr int NG = 64 / GL;    // edges per step
  int wid = (blockIdx.x * 256 + threadIdx.x) >> 6;
  int lane = threadIdx.x & 63;
  if (wid >= NN) return;
  int i = __builtin_amdgcn_readfirstlane(wid);
  int2 ri = rowinfo[i];
  int rs = ri.x, m = ri.y;
  int g = lane / GL;
  int f = lane % GL;             // 8-half chunk index
  const int* __restrict__ sp = srcs + rs;

  float acc[8];
  #pragma unroll
  for (int q = 0; q < 8; ++q) acc[q] = 0.f;

  #pragma unroll 4
  for (int e = g; e < m; e += NG) {
    int src = sp[e];
    half8 v = *(const half8*)(hin + (size_t)src * W + f * 8);
    #pragma unroll
    for (int q = 0; q < 8; ++q) acc[q] += (float)v[q];
  }
  #pragma unroll
  for (int q = 0; q < 8; ++q) {
    #pragma unroll
    for (int off = GL; off < 64; off <<= 1) acc[q] += __shfl_xor(acc[q], off);
  }
  float cm = fmaxf((float)m, 1.f);
  if (lane < GL) {
    _Float16 o[8];
    #pragma unroll
    for (int q = 0; q < 8; ++q) o[q] = (_Float16)(acc[q] / cm);
    *(half8*)(meanout + (size_t)i * W + lane * 8) = *(half8*)o;
  }
}

// ---------------- MFMA MLP with LDS-staged weights: relu(mean@Wl + b + h@Wr [+ h]); FINAL fuses fc ----------------
// mfma_f32_16x16x32_f16: A row=lane&15, k=(lane>>4)*8+j ; D col=lane&15, row=(lane>>4)*4+reg (HW-validated R6-R8)
template <int W, int KW, bool RES, bool FINAL>
__global__ __launch_bounds__(256) void k_mlp(const _Float16* __restrict__ mean,
    const _Float16* __restrict__ h,
    const float* __restrict__ Wl, const float* __restrict__ bl,
    const float* __restrict__ Wr,
    const float* __restrict__ Wfc, const float* __restrict__ bfc,
    void* __restrict__ outp)
{
  __shared__ _Float16 lwl[64 * W];   // transposed [n][k]
  __shared__ _Float16 lwr[64 * W];
  int tid = threadIdx.x;
  for (int idx = tid; idx < 64 * W; idx += 256) {
    int nn = idx / W, kk = idx % W;
    lwl[idx] = (kk < KW) ? (_Float16)Wl[kk * 64 + nn] : (_Float16)0.f;
    lwr[idx] = (kk < KW) ? (_Float16)Wr[kk * 64 + nn] : (_Float16)0.f;
  }
  __syncthreads();
  constexpr int NKB = W / 32;
  int wv = tid >> 6, lane = tid & 63;
  int c = lane & 15, kg = lane >> 4;

  half8 bwl[4][NKB], bwr[4][NKB];
  #pragma unroll
  for (int nt = 0; nt < 4; ++nt)
    #pragma unroll
    for (int kb = 0; kb < NKB; ++kb) {
      bwl[nt][kb] = *(const half8*)&lwl[(nt * 16 + c) * W + kb * 32 + kg * 8];
      bwr[nt][kb] = *(const half8*)&lwr[(nt * 16 + c) * W + kb * 32 + kg * 8];
    }

  int wavebase = blockIdx.x * 256 + wv * 64;
  #pragma unroll
  for (int ti = 0; ti < 4; ++ti) {
    int tbase = wavebase + ti * 16;     // NN % 16 == 0: tiles fully valid or fully out
    if (tbase >= NN) break;
    half8 am[NKB], ah[NKB];
    #pragma unroll
    for (int kb = 0; kb < NKB; ++kb) {
      am[kb] = *(const half8*)(mean + (size_t)(tbase + c) * W + kb * 32 + kg * 8);
      ah[kb] = *(const half8*)(h    + (size_t)(tbase + c) * W + kb * 32 + kg * 8);
    }
    f32x4 acc[4] = {f32x4{0,0,0,0}, f32x4{0,0,0,0}, f32x4{0,0,0,0}, f32x4{0,0,0,0}};
    #pragma unroll
    for (int nt = 0; nt < 4; ++nt)
      #pragma unroll
      for (int kb = 0; kb < NKB; ++kb) {
        acc[nt] = __builtin_amdgcn_mfma_f32_16x16x32_f16(am[kb], bwl[nt][kb], acc[nt], 0, 0, 0);
        acc[nt] = __builtin_amdgcn_mfma_f32_16x16x32_f16(ah[kb], bwr[nt][kb], acc[nt], 0, 0, 0);
      }
    if (!FINAL) {
      _Float16* hout = (_Float16*)outp;
      #pragma unroll
      for (int nt = 0; nt < 4; ++nt) {
        float bia = bl[nt * 16 + c];
        #pragma unroll
        for (int r = 0; r < 4; ++r) {
          int node = tbase + kg * 4 + r;
          float v = acc[nt][r] + bia;
          if (RES) v += (float)h[(size_t)node * 64 + nt * 16 + c];
          hout[(size_t)node * 64 + nt * 16 + c] = (_Float16)fmaxf(v, 0.f);
        }
      }
    } else {
      #pragma unroll
      for (int r = 0; r < 4; ++r) {
        float p = 0.f;
        #pragma unroll
        for (int nt = 0; nt < 4; ++nt) {
          float v = acc[nt][r] + bl[nt * 16 + c];
          if (RES) v += (float)h[(size_t)(tbase + kg * 4 + r) * 64 + nt * 16 + c];
          v = fmaxf(v, 0.f);
          p = fmaf(v, Wfc[nt * 16 + c], p);
        }
        p += __shfl_xor(p, 1); p += __shfl_xor(p, 2);
        p += __shfl_xor(p, 4); p += __shfl_xor(p, 8);
        if (c == 0) ((float*)outp)[tbase + kg * 4 + r] = p + bfc[0];
      }
    }
  }
}

// ---------------- launch ----------------
extern "C" void kernel_launch(void* const* d_in, const int* in_sizes, int n_in,
                              void* d_out, int out_size, void* d_ws, size_t ws_size,
                              hipStream_t stream)
{
  const float* x   = (const float*)d_in[0];
  const int*   ei  = (const int*)d_in[1];
  const float* We  = (const float*)d_in[2];
  const float* be  = (const float*)d_in[3];
  const float* lg  = (const float*)d_in[4];
  const float* lb  = (const float*)d_in[5];
  const float* Wl1 = (const float*)d_in[6];
  const float* bl1 = (const float*)d_in[7];
  const float* Wr1 = (const float*)d_in[8];
  const float* Wl2 = (const float*)d_in[9];
  const float* bl2 = (const float*)d_in[10];
  const float* Wr2 = (const float*)d_in[11];
  const float* Wl3 = (const float*)d_in[12];
  const float* bl3 = (const float*)d_in[13];
  const float* Wr3 = (const float*)d_in[14];
  const float* Wfc = (const float*)d_in[15];
  const float* bfc = (const float*)d_in[16];
  (void)in_sizes; (void)n_in; (void)out_size; (void)ws_size;

  size_t off = 0;
  auto carve = [&](size_t bytes) -> void* {
    void* p = (char*)d_ws + off;
    off += (bytes + 255) & ~(size_t)255;
    return p;
  };
  _Float16* h0p    = (_Float16*)carve((size_t)NN * 32 * 2);        // 6.4 MB
  _Float16* mean1  = (_Float16*)carve((size_t)NN * 32 * 2);        // 6.4 MB
  // union: ebuf (13.85 MB, dead after k_partB) aliases h1 (12.8 MB, first written by layer-1 mlp)
  char*     uni    = (char*)carve((size_t)NB1 * BCAP2 * 4);        // 13.85 MB
  int*      ebuf   = (int*)uni;
  _Float16* h1     = (_Float16*)uni;
  _Float16* mean23 = (_Float16*)carve((size_t)NN * 64 * 2);        // 12.8 MB
  _Float16* h2     = (_Float16*)carve((size_t)NN * 64 * 2);        // 12.8 MB
  int*      srcs   = (int*)carve((size_t)NB1 * BCAP2 * 4);         // 13.85 MB
  int2*     rowinfo= (int2*)carve((size_t)NN * 8);                 // 0.8 MB
  int*      gcur   = (int*)carve((size_t)NB1 * 4);

  const int nblk_node = (NN + 255) / 256;          // 391
  const int nblk_wave = (NN + 3) / 4;              // 25000 (4 waves/block, 1 wave/node)

  hipMemsetAsync(gcur, 0, (size_t)NB1 * 4, stream);
  k_h0<<<nblk_node, 256, 0, stream>>>(x, We, be, lg, lb, h0p);
  k_partA<<<NPB, 256, 0, stream>>>(ei, gcur, ebuf);
  k_partB<<<NB1, 512, 0, stream>>>(gcur, ebuf, rowinfo, srcs);

  // layer 1
  k_agg<32><<<nblk_wave, 256, 0, stream>>>(h0p, rowinfo, srcs, mean1);
  k_mlp<32, 17, false, false><<<nblk_node, 256, 0, stream>>>(mean1, h0p, Wl1, bl1, Wr1, nullptr, nullptr, h1);
  // layer 2
  k_agg<64><<<nblk_wave, 256, 0, stream>>>(h1, rowinfo, srcs, mean23);
  k_mlp<64, 64, true, false><<<nblk_node, 256, 0, stream>>>(mean23, h1, Wl2, bl2, Wr2, nullptr, nullptr, h2);
  // layer 3 + fc
  k_agg<64><<<nblk_wave, 256, 0, stream>>>(h2, rowinfo, srcs, mean23);
  k_mlp<64, 64, true, true><<<nblk_node, 256, 0, stream>>>(mean23, h2, Wl3, bl3, Wr3, Wfc, bfc, d_out);
}